// Round 4
// baseline (877.279 us; speedup 1.0000x reference)
//
#include <hip/hip_runtime.h>

typedef _Float16 half8 __attribute__((ext_vector_type(8)));
typedef float floatx4 __attribute__((ext_vector_type(4)));

#define K_IN 4096
#define N_OUT 4096
#define NGROUPS 32
#define BM 128
#define BN 128
#define LDA 40  // padded LDS row stride (f16 elems)

__device__ __forceinline__ unsigned int pkcvt(float lo, float hi) {
    // v_cvt_pkrtz_f16_f32: element0 <- lo, element1 <- hi
    return __builtin_bit_cast(unsigned int, __builtin_amdgcn_cvt_pkrtz(lo, hi));
}

__global__ __launch_bounds__(256, 2)
void gptq_gemm_f32(const float* __restrict__ x,        // [M,K] fp32 (fp16-origin)
                   const int*   __restrict__ qweight,  // [K/8, N] nibbles along K
                   const int*   __restrict__ qzeros,   // [G, N/8] nibbles along N
                   const float* __restrict__ scales,   // [G, N] fp32
                   const float* __restrict__ bias,     // [N] fp32
                   float*       __restrict__ out)      // [M, N] fp32
{
    __shared__ alignas(16) _Float16 As[BM * LDA];

    const int tid  = threadIdx.x;
    const int lane = tid & 63;
    const int wave = tid >> 6;
    const int wm   = wave >> 1;   // wave row (64 M each)
    const int wn   = wave & 1;    // wave col (64 N each)
    const int l15  = lane & 15;
    const int l4   = lane >> 4;   // quad 0..3

    const int blockN = blockIdx.x * BN;
    const int blockM = blockIdx.y * BM;

    floatx4 acc[4][4] = {};

    // A staging: thread stages rows (tid>>2) and (tid>>2)+64, 8-float chunk (tid&3)
    const int srow = tid >> 2;
    const int sch  = tid & 3;
    const float* xr0 = x + (size_t)(blockM + srow) * K_IN + sch * 8;
    const float* xr1 = xr0 + (size_t)64 * K_IN;
    _Float16* lds0 = &As[srow * LDA + sch * 8];
    _Float16* lds1 = &As[(srow + 64) * LDA + sch * 8];

    int ncol[4];
#pragma unroll
    for (int j = 0; j < 4; ++j) ncol[j] = blockN + wn * 64 + j * 16 + l15;

    for (int g = 0; g < NGROUPS; ++g) {
        // dequant constants: w = nib * s - (z+1) * s
        float sf[4], cf[4];
#pragma unroll
        for (int j = 0; j < 4; ++j) {
            const int n = ncol[j];
            const unsigned int zq = (unsigned int)qzeros[g * (N_OUT / 8) + (n >> 3)];
            const float zp1 = (float)(((zq >> ((n & 7) * 4)) & 0xFu) + 1u);
            const float s   = scales[g * N_OUT + n];
            sf[j] = s;
            cf[j] = -zp1 * s;
        }

#pragma unroll
        for (int kk = 0; kk < 4; ++kk) {
            const int k0 = g * 128 + kk * 32;

            __syncthreads();
            // ---- stage A tile: fp32 -> f16 (exact, fp16-origin values) ----
            {
                const float4 a0 = *(const float4*)(xr0 + k0);
                const float4 a1 = *(const float4*)(xr0 + k0 + 4);
                const float4 b0 = *(const float4*)(xr1 + k0);
                const float4 b1 = *(const float4*)(xr1 + k0 + 4);
                uint4 ra, rb;
                ra.x = pkcvt(a0.x, a0.y);  ra.y = pkcvt(a0.z, a0.w);
                ra.z = pkcvt(a1.x, a1.y);  ra.w = pkcvt(a1.z, a1.w);
                rb.x = pkcvt(b0.x, b0.y);  rb.y = pkcvt(b0.z, b0.w);
                rb.z = pkcvt(b1.x, b1.y);  rb.w = pkcvt(b1.z, b1.w);
                *(uint4*)(void*)lds0 = ra;
                *(uint4*)(void*)lds1 = rb;
            }
            __syncthreads();

            // ---- B fragments: fp32 dequant per nibble, natural k order ----
            const int* qrow = qweight + (size_t)((k0 >> 3) + l4) * N_OUT;
            half8 bfrag[4];
#pragma unroll
            for (int j = 0; j < 4; ++j) {
                const unsigned int q = (unsigned int)qrow[ncol[j]];
                const float s = sf[j], c = cf[j];
                float w[8];
#pragma unroll
                for (int e = 0; e < 8; ++e)
                    w[e] = fmaf((float)((q >> (4 * e)) & 0xFu), s, c);
                union { unsigned int u[4]; half8 h; } pk;
                pk.u[0] = pkcvt(w[0], w[1]);
                pk.u[1] = pkcvt(w[2], w[3]);
                pk.u[2] = pkcvt(w[4], w[5]);
                pk.u[3] = pkcvt(w[6], w[7]);
                bfrag[j] = pk.h;
            }

            // ---- A fragments from LDS: A[m = l15][k = l4*8 + e] ----
            half8 afrag[4];
#pragma unroll
            for (int i = 0; i < 4; ++i)
                afrag[i] = *(const half8*)(const void*)&As[(wm * 64 + i * 16 + l15) * LDA + l4 * 8];

#pragma unroll
            for (int i = 0; i < 4; ++i)
#pragma unroll
                for (int j = 0; j < 4; ++j)
                    acc[i][j] = __builtin_amdgcn_mfma_f32_16x16x32_f16(
                        afrag[i], bfrag[j], acc[i][j], 0, 0, 0);
        }
    }

    // ---- epilogue: fp32 out; C layout col=lane&15, row=(lane>>4)*4+reg ----
#pragma unroll
    for (int j = 0; j < 4; ++j) {
        const int n = ncol[j];
        const float bv = bias[n];
#pragma unroll
        for (int i = 0; i < 4; ++i) {
            const int m = blockM + wm * 64 + i * 16 + l4 * 4;
#pragma unroll
            for (int r = 0; r < 4; ++r)
                out[(size_t)(m + r) * N_OUT + n] = acc[i][j][r] + bv;
        }
    }
}

extern "C" void kernel_launch(void* const* d_in, const int* in_sizes, int n_in,
                              void* d_out, int out_size, void* d_ws, size_t ws_size,
                              hipStream_t stream) {
    const float* x    = (const float*)d_in[0];
    const int*   qw   = (const int*)d_in[1];
    const int*   qz   = (const int*)d_in[2];
    const float* sc   = (const float*)d_in[3];
    const float* bias = (const float*)d_in[4];
    float*       out  = (float*)d_out;

    const int M = in_sizes[0] / K_IN;   // 8192
    dim3 grid(N_OUT / BN, M / BM);      // (32, 64)
    gptq_gemm_f32<<<grid, 256, 0, stream>>>(x, qw, qz, sc, bias, out);
}

// Round 5
// 553.513 us; speedup vs baseline: 1.5849x; 1.5849x over previous
//
#include <hip/hip_runtime.h>

typedef _Float16 half8 __attribute__((ext_vector_type(8)));
typedef _Float16 half2v __attribute__((ext_vector_type(2)));
typedef float floatx4 __attribute__((ext_vector_type(4)));

#define K_IN 4096
#define N_OUT 4096
#define NGROUPS 32
#define BM 128
#define BN 128
#define LDA 40   // padded LDS row stride (f16): 80 B = 20 banks, ~2-way max

__device__ __forceinline__ unsigned int pkcvt(float lo, float hi) {
    // v_cvt_pkrtz_f16_f32: element0 <- lo, element1 <- hi (fp16-origin fp32 -> exact)
    return __builtin_bit_cast(unsigned int, __builtin_amdgcn_cvt_pkrtz(lo, hi));
}

__global__ __launch_bounds__(256, 2)
void gptq_gemm_f32(const float* __restrict__ x,        // [M,K] fp32 (fp16-origin)
                   const int*   __restrict__ qweight,  // [K/8, N] nibbles along K
                   const int*   __restrict__ qzeros,   // [G, N/8] nibbles along N
                   const float* __restrict__ scales,   // [G, N] fp32
                   const float* __restrict__ bias,     // [N] fp32
                   float*       __restrict__ out)      // [M, N] fp32
{
    // double-buffered A tile; k-order within each 8-chunk is [0,4,1,5,2,6,3,7]
    __shared__ alignas(16) _Float16 As[2][BM * LDA];

    const int tid  = threadIdx.x;
    const int lane = tid & 63;
    const int wave = tid >> 6;
    const int wm   = wave >> 1;
    const int wn   = wave & 1;
    const int l15  = lane & 15;
    const int l4   = lane >> 4;

    const int blockN = blockIdx.x * BN;
    const int blockM = blockIdx.y * BM;

    floatx4 acc[4][4] = {};

    const int srow = tid >> 2;
    const int sch  = tid & 3;
    const float* xr0 = x + (size_t)(blockM + srow) * K_IN + sch * 8;
    const float* xr1 = xr0 + (size_t)64 * K_IN;
    _Float16* lw0 = &As[0][srow * LDA + sch * 8];
    _Float16* lw1 = &As[0][(srow + 64) * LDA + sch * 8];

    int ncol[4];
#pragma unroll
    for (int j = 0; j < 4; ++j) ncol[j] = blockN + wn * 64 + j * 16 + l15;

    // ---- prologue: raw group-0 consts + step-0 A/B prefetch ----
    unsigned int zraw[4]; float sraw[4];
#pragma unroll
    for (int j = 0; j < 4; ++j) {
        zraw[j] = (unsigned int)qzeros[ncol[j] >> 3];
        sraw[j] = scales[ncol[j]];
    }
    float4 pa0 = *(const float4*)(xr0);
    float4 pa1 = *(const float4*)(xr0 + 4);
    float4 pb0 = *(const float4*)(xr1);
    float4 pb1 = *(const float4*)(xr1 + 4);
    unsigned int pq[4];
    {
        const int* qr = qweight + (size_t)l4 * N_OUT;
#pragma unroll
        for (int j = 0; j < 4; ++j) pq[j] = (unsigned int)qr[ncol[j]];
    }

    for (int g = 0; g < NGROUPS; ++g) {
        // packed f16 consts for this group: c2 = 1024+(z+1) (exact), s2 = f16(scale)
        unsigned int c2u[4], s2u[4];
#pragma unroll
        for (int j = 0; j < 4; ++j) {
            const unsigned int z  = (zraw[j] >> ((ncol[j] & 7) * 4)) & 0xFu;
            const unsigned int cb = 0x6400u + z + 1u;
            c2u[j] = cb | (cb << 16);
            s2u[j] = pkcvt(sraw[j], sraw[j]);
        }
        // prefetch next group's raws (clamped; redundant last load is harmless)
        const int gn = (g + 1 < NGROUPS) ? g + 1 : g;
#pragma unroll
        for (int j = 0; j < 4; ++j) {
            zraw[j] = (unsigned int)qzeros[gn * (N_OUT / 8) + (ncol[j] >> 3)];
            sraw[j] = scales[gn * N_OUT + ncol[j]];
        }

#pragma unroll
        for (int kk = 0; kk < 4; ++kk) {
            const int t   = g * 4 + kk;
            const int buf = t & 1;

            // ---- stage prefetched A -> LDS[buf], interleaved pairs (k, k+4) ----
            uint4 ra, rb;
            ra.x = pkcvt(pa0.x, pa1.x);  ra.y = pkcvt(pa0.y, pa1.y);
            ra.z = pkcvt(pa0.z, pa1.z);  ra.w = pkcvt(pa0.w, pa1.w);
            rb.x = pkcvt(pb0.x, pb1.x);  rb.y = pkcvt(pb0.y, pb1.y);
            rb.z = pkcvt(pb0.z, pb1.z);  rb.w = pkcvt(pb0.w, pb1.w);
            *(uint4*)(void*)(lw0 + buf * (BM * LDA)) = ra;
            *(uint4*)(void*)(lw1 + buf * (BM * LDA)) = rb;

            unsigned int bq[4] = {pq[0], pq[1], pq[2], pq[3]};

            // ---- issue next step's global loads (in flight across barrier) ----
            const int t1 = (t + 1 < 4 * NGROUPS) ? t + 1 : t;
            pa0 = *(const float4*)(xr0 + t1 * 32);
            pa1 = *(const float4*)(xr0 + t1 * 32 + 4);
            pb0 = *(const float4*)(xr1 + t1 * 32);
            pb1 = *(const float4*)(xr1 + t1 * 32 + 4);
            {
                const int* qr = qweight + (size_t)(t1 * 4 + l4) * N_OUT;
#pragma unroll
                for (int j = 0; j < 4; ++j) pq[j] = (unsigned int)qr[ncol[j]];
            }

            __syncthreads();   // single barrier per step (double buffer)

            // ---- B dequant: packed f16 (m - c2) * s2, pairs (k, k+4) ----
            half8 bfrag[4];
#pragma unroll
            for (int j = 0; j < 4; ++j) {
                const unsigned int q = bq[j];
                const unsigned int r0 = (q & 0x000F000Fu)        | 0x64006400u;
                const unsigned int r1 = ((q >> 4) & 0x000F000Fu) | 0x64006400u;
                const unsigned int r2 = ((q >> 8) & 0x000F000Fu) | 0x64006400u;
                const unsigned int r3 = ((q >> 12) & 0x000F000Fu)| 0x64006400u;
                const half2v c2 = __builtin_bit_cast(half2v, c2u[j]);
                const half2v s2 = __builtin_bit_cast(half2v, s2u[j]);
                union { unsigned int u[4]; half8 h; } pk;
                pk.u[0] = __builtin_bit_cast(unsigned int,
                          (half2v)((__builtin_bit_cast(half2v, r0) - c2) * s2));
                pk.u[1] = __builtin_bit_cast(unsigned int,
                          (half2v)((__builtin_bit_cast(half2v, r1) - c2) * s2));
                pk.u[2] = __builtin_bit_cast(unsigned int,
                          (half2v)((__builtin_bit_cast(half2v, r2) - c2) * s2));
                pk.u[3] = __builtin_bit_cast(unsigned int,
                          (half2v)((__builtin_bit_cast(half2v, r3) - c2) * s2));
                bfrag[j] = pk.h;
            }

            // ---- A fragments from LDS[buf] (same interleaved k-order) ----
            half8 afrag[4];
#pragma unroll
            for (int i = 0; i < 4; ++i)
                afrag[i] = *(const half8*)(const void*)
                    &As[buf][(wm * 64 + i * 16 + l15) * LDA + l4 * 8];

#pragma unroll
            for (int i = 0; i < 4; ++i)
#pragma unroll
                for (int j = 0; j < 4; ++j)
                    acc[i][j] = __builtin_amdgcn_mfma_f32_16x16x32_f16(
                        afrag[i], bfrag[j], acc[i][j], 0, 0, 0);
        }
    }

    // ---- epilogue: C layout col=lane&15, row=(lane>>4)*4+reg ----
#pragma unroll
    for (int j = 0; j < 4; ++j) {
        const int n = ncol[j];
        const float bv = bias[n];
#pragma unroll
        for (int i = 0; i < 4; ++i) {
            const int m = blockM + wm * 64 + i * 16 + l4 * 4;
#pragma unroll
            for (int r = 0; r < 4; ++r)
                out[(size_t)(m + r) * N_OUT + n] = acc[i][j][r] + bv;
        }
    }
}

extern "C" void kernel_launch(void* const* d_in, const int* in_sizes, int n_in,
                              void* d_out, int out_size, void* d_ws, size_t ws_size,
                              hipStream_t stream) {
    const float* x    = (const float*)d_in[0];
    const int*   qw   = (const int*)d_in[1];
    const int*   qz   = (const int*)d_in[2];
    const float* sc   = (const float*)d_in[3];
    const float* bias = (const float*)d_in[4];
    float*       out  = (float*)d_out;

    const int M = in_sizes[0] / K_IN;   // 8192
    dim3 grid(N_OUT / BN, M / BM);      // (32, 64)
    gptq_gemm_f32<<<grid, 256, 0, stream>>>(x, qw, qz, sc, bias, out);
}